// Round 1
// 91.585 us; speedup vs baseline: 1.0048x; 1.0048x over previous
//
#include <hip/hip_runtime.h>
#include <math.h>

#define NATOMS    128
#define NSEG      7875     // segments: i in [0,124], j in [i+2,126]
#define NSEG_PAD  8192     // padded so Phase A needs no predication
#define NPAIR     8128     // pairs (a,b), 0 <= a < b <= 127
#define OUT_PER_B 16256    // 128*127 (row-major, diagonal skipped)
#define BLOCK     512

typedef float v2f __attribute__((ext_vector_type(2)));
__device__ __forceinline__ v2f mk2(float a, float b) { v2f r; r.x = a; r.y = b; return r; }

struct P3 { v2f x, y, z; };
__device__ __forceinline__ P3 psub(P3 a, P3 b) { return {a.x - b.x, a.y - b.y, a.z - b.z}; }
__device__ __forceinline__ P3 pcross(P3 a, P3 b) {
    return {a.y * b.z - a.z * b.y, a.z * b.x - a.x * b.z, a.x * b.y - a.y * b.x};
}
__device__ __forceinline__ v2f pdot(P3 a, P3 b) { return a.x * b.x + a.y * b.y + a.z * b.z; }
__device__ __forceinline__ v2f prsq(v2f q) {
    v2f r; r.x = __builtin_amdgcn_rsqf(q.x); r.y = __builtin_amdgcn_rsqf(q.y); return r;
}
__device__ __forceinline__ v2f pclip1(v2f x) {
    return __builtin_elementwise_min(__builtin_elementwise_max(x, mk2(-1.f, -1.f)),
                                     mk2(1.f, 1.f));
}

// Packed 4-term branchless asin, A&S 4.4.45 (|err| <= 6.8e-5; threshold 5.9e-2).
__device__ __forceinline__ v2f fast_asin2(v2f x) {
    v2f a = __builtin_elementwise_abs(x);
    v2f p = mk2(-0.0187293f, -0.0187293f);
    p = p * a + mk2( 0.0742610f,  0.0742610f);
    p = p * a + mk2(-0.2121144f, -0.2121144f);
    p = p * a + mk2( 1.5707288f,  1.5707288f);
    v2f om = mk2(1.0f, 1.0f) - a;
    v2f sq; sq.x = __builtin_amdgcn_sqrtf(om.x); sq.y = __builtin_amdgcn_sqrtf(om.y);
    v2f r = mk2(1.57079632679f, 1.57079632679f) - sq * p;
    return __builtin_elementwise_copysign(r, x);
}

__device__ __forceinline__ int seg_row_base(int i) { return 125 * i - (__umul24(i, i - 1) >> 1); }

// Writhe for TWO packed segments (x-lane = pa, y-lane = pb), all 3D math in
// packed f32 (v_pk_*). Sign via the exact identity
//   cross(p3-p2, p1-p0) . u0 = -(u3 x u2) . u0 = -n2 . u0
// (expand (u3-u2)x(u0-u2).u0; the u0- and u2-triple products vanish), which
// deletes the axial cross entirely.
__device__ __forceinline__ v2f seg_writhe_pair(unsigned pa, unsigned pb,
                                               const float* sx, const float* sy,
                                               const float* sz) {
    int jA = (int)(pa & 127u), iA = (int)(pa >> 7);
    int jB = (int)(pb & 127u), iB = (int)(pb >> 7);

    P3 p0 = {mk2(sx[iA],     sx[iB]),     mk2(sy[iA],     sy[iB]),     mk2(sz[iA],     sz[iB])};
    P3 p1 = {mk2(sx[iA + 1], sx[iB + 1]), mk2(sy[iA + 1], sy[iB + 1]), mk2(sz[iA + 1], sz[iB + 1])};
    P3 p2 = {mk2(sx[jA],     sx[jB]),     mk2(sy[jA],     sy[jB]),     mk2(sz[jA],     sz[jB])};
    P3 p3 = {mk2(sx[jA + 1], sx[jB + 1]), mk2(sy[jA + 1], sy[jB + 1]), mk2(sz[jA + 1], sz[jB + 1])};

    P3 u0 = psub(p2, p0);
    P3 u1 = psub(p3, p0);
    P3 u2 = psub(p2, p1);
    P3 u3 = psub(p3, p1);

    P3 n0 = pcross(u0, u1);
    P3 n1 = pcross(u1, u3);
    P3 n2 = pcross(u3, u2);
    P3 n3 = pcross(u2, u0);

    v2f q0 = pdot(n0, n0);
    v2f q1 = pdot(n1, n1);
    v2f q2 = pdot(n2, n2);
    v2f q3 = pdot(n3, n3);

    v2f c0 = pclip1(pdot(n0, n1) * prsq(q0 * q1));
    v2f c1 = pclip1(pdot(n1, n2) * prsq(q1 * q2));
    v2f c2 = pclip1(pdot(n2, n3) * prsq(q2 * q3));
    v2f c3 = pclip1(pdot(n3, n0) * prsq(q3 * q0));

    v2f sd = pdot(n2, u0);     // = -(reference sd); sign folded below
    v2f omega = fast_asin2(c0) + fast_asin2(c1) + fast_asin2(c2) + fast_asin2(c3);

    v2f sgn;
    sgn.x = (sd.x > 0.f) ? -1.f : ((sd.x < 0.f) ? 1.f : 0.f);
    sgn.y = (sd.y > 0.f) ? -1.f : ((sd.y < 0.f) ? 1.f : 0.f);

    return omega * sgn * mk2(0.15915494309189535f, 0.15915494309189535f);
}

// One block per batch.
// Phase 0: u16 segment index table (sidx, padded to 8192). spair table DROPPED:
//          Phase D now inverts the output index arithmetically.
// Phase A: packed-pair writhe -> swr (padded, unconditional), 2 independent
//          packed chains per iteration x 4 iterations = 16 segments/thread.
// Phase D: OUTPUT-ROW-MAJOR. Each thread computes 4 consecutive output
//          elements (k -> (r,c) via exact magic-div by 127, (a,b) = sorted),
//          gathers 4 swr values from LDS, stores ONE coalesced float4.
//          Each pair-sum is computed twice (both triangle sides) -- 2x the
//          cheap LDS gathers in exchange for zero scattered stores.
// Occupancy: BLOCK=512, __launch_bounds__(512,4): VGPR cap 128 (the two
//          packed writhe chains need ~100 live VGPRs -- the old (1024,8)
//          config capped at 64 and strangled Phase A). LDS = 1.5K + 32K
//          + 16K ~= 49.5 KB -> 2 blocks/CU (grid 512 = 2/CU, fully resident).
__global__ __launch_bounds__(BLOCK, 4) void writhe_fused(
    const float* __restrict__ xyz,       // (B, 128, 3)
    float*       __restrict__ out)       // (B, 16256)
{
    __shared__ float sx[NATOMS], sy[NATOMS], sz[NATOMS];
    __shared__ float swr[NSEG_PAD];
    __shared__ unsigned short sidx[NSEG_PAD];

    const int b = blockIdx.x;
    const int t = threadIdx.x;

    if (t < 3 * NATOMS) {
        float v = xyz[(size_t)b * (3 * NATOMS) + t];
        int a = t / 3, c = t - 3 * a;
        if (c == 0) sx[a] = v; else if (c == 1) sy[a] = v; else sz[a] = v;
    }

    // ---------- Phase 0: build sidx (+ pad tail with a safe segment) ----------
    {
        int s = t * 16;
        if (s < NSEG) {
            int i = (int)((251.0f - __builtin_amdgcn_sqrtf(63001.0f - 8.0f * (float)s)) * 0.5f);
            i = max(i, 0);
            i += (seg_row_base(i + 1) <= s);
            i += (seg_row_base(i + 1) <= s);
            i -= (seg_row_base(i) > s);
            i -= (seg_row_base(i) > s);
            int j = s - seg_row_base(i) + i + 2;
            #pragma unroll
            for (int k = 0; k < 16; ++k) {
                if (s < NSEG) sidx[s] = (unsigned short)((i << 7) | j);
                ++s; ++j;
                if (j > 126) { ++i; j = i + 2; }
            }
        }
        if (t < NSEG_PAD - NSEG) sidx[NSEG + t] = (unsigned short)((124 << 7) | 126);
    }
    __syncthreads();

    // ---------- Phase A: packed-pair writhe, 2 chains x 4 iterations ----------
    #pragma unroll
    for (int g = 0; g < 4; ++g) {
        const int sA = g * 2048 + t;     // sA..sA+1536 < 8192: unconditional
        v2f w1 = seg_writhe_pair(sidx[sA],        sidx[sA + 512],  sx, sy, sz);
        v2f w2 = seg_writhe_pair(sidx[sA + 1024], sidx[sA + 1536], sx, sy, sz);
        swr[sA]        = w1.x;
        swr[sA + 512]  = w1.y;
        swr[sA + 1024] = w2.x;
        swr[sA + 1536] = w2.y;
    }
    __syncthreads();

    // ---------- Phase D: row-major gather + coalesced float4 store ----------
    // k in [0, 16256): r = k/127 (exact magic mul: 16255*132105 < 2^31),
    // c' = k%127, c = c' + (c' >= r); (a,b) = (min,max)(r,c).
    float* ob = out + (size_t)b * OUT_PER_B;
    for (int kq = t; kq < OUT_PER_B / 4; kq += BLOCK) {
        const int k0 = kq << 2;
        float acc[4];
        #pragma unroll
        for (int q = 0; q < 4; ++q) {
            const int k = k0 + q;
            const int r = (int)(((unsigned)k * 132105u) >> 24);
            int c = k - r * 127;
            c += (c >= r);
            const int a  = min(r, c);
            const int bb = max(r, c);

            // segment ids for (i,j) in {a-1,a} x {b-1,b}; s(i,j)=base(i)+j-i-2
            const int am1 = a - 1;
            const int s00 = 125 * am1 - ((am1 * (am1 - 1)) >> 1) + bb - a - 2;  // (a-1, b-1)
            const int s10 = s00 + 125 - a;                                      // (a,   b-1)

            const bool v00 = (a >= 1) && (a <= 125) && (bb >= a + 2);
            const bool v01 = (a >= 1) && (a <= 125) && (bb <= 126);
            const bool v10 = (a <= 124) && (bb >= a + 3);
            const bool v11 = (a <= 124) && (bb <= 126) && (bb >= a + 2);

            const int c00 = min(max(s00,     0), NSEG - 1);
            const int c01 = min(max(s00 + 1, 0), NSEG - 1);
            const int c10 = min(max(s10,     0), NSEG - 1);
            const int c11 = min(max(s10 + 1, 0), NSEG - 1);

            acc[q] = (v00 ? swr[c00] : 0.0f) + (v01 ? swr[c01] : 0.0f)
                   + (v10 ? swr[c10] : 0.0f) + (v11 ? swr[c11] : 0.0f);
        }
        float4 res; res.x = acc[0]; res.y = acc[1]; res.z = acc[2]; res.w = acc[3];
        *reinterpret_cast<float4*>(ob + k0) = res;   // 16B-aligned: 16256 % 4 == 0
    }
}

extern "C" void kernel_launch(void* const* d_in, const int* in_sizes, int n_in,
                              void* d_out, int out_size, void* d_ws, size_t ws_size,
                              hipStream_t stream) {
    const float* xyz = (const float*)d_in[0];
    float*       out = (float*)d_out;

    int B = in_sizes[0] / (NATOMS * 3);   // 512 for the reference shapes
    writhe_fused<<<B, BLOCK, 0, stream>>>(xyz, out);
}